// Round 13
// baseline (430.683 us; speedup 1.0000x reference)
//
#include <hip/hip_runtime.h>

#define N_NODES 100000
#define N_EDGES 1600000

typedef _Float16 f16x8 __attribute__((ext_vector_type(8)));
typedef _Float16 f16x4 __attribute__((ext_vector_type(4)));
typedef float fx4 __attribute__((ext_vector_type(4)));

#define NREP 16     // stats-accumulator replication to de-contend atomics
#define NBUCK 196   // ceil(100000/512) buckets of 512 nodes
#define CHUNK 8192  // edges per k_bin block
#define BCAP 12288  // per-bucket slot capacity

// ---------------- CSR build, pass 1: LDS counting-sort chunks by bucket --------
__global__ __launch_bounds__(256) void k_bin(const int* __restrict__ ei,
                                             unsigned* __restrict__ binned,
                                             int* __restrict__ gcount) {
  __shared__ unsigned pr[CHUNK];
  __shared__ unsigned srt[CHUNK];
  __shared__ unsigned char bk[CHUNK];
  __shared__ int hist[256], scanb[256], offs[256], bs[256], gb[256];
  const int t = threadIdx.x;
  const int e0 = blockIdx.x * CHUNK;
  const int n = min(CHUNK, N_EDGES - e0);
  hist[t] = 0;
  __syncthreads();
  for (int i = t; i < n; i += 256) {
    int src = ei[e0 + i], dst = ei[N_EDGES + e0 + i];
    int b = dst >> 9;
    pr[i] = ((unsigned)src << 9) | (unsigned)(dst & 511);
    bk[i] = (unsigned char)b;
    atomicAdd(&hist[b], 1);
  }
  __syncthreads();
  int v = hist[t];
  scanb[t] = v;
  __syncthreads();
  for (int off = 1; off < 256; off <<= 1) {
    int a = (t >= off) ? scanb[t - off] : 0;
    __syncthreads();
    scanb[t] += a;
    __syncthreads();
  }
  offs[t] = scanb[t] - v;
  bs[t] = scanb[t] - v;
  __syncthreads();
  for (int i = t; i < n; i += 256) {
    int b = bk[i];
    int p = atomicAdd(&offs[b], 1);
    srt[p] = pr[i];
  }
  if (t < NBUCK && v > 0) gb[t] = atomicAdd(&gcount[t], v);
  __syncthreads();
  int wave = t >> 6, lane = t & 63;
  for (int b = wave; b < NBUCK; b += 4) {
    int c = hist[b];
    if (c == 0) continue;
    int ls = bs[b], base = gb[b];
    unsigned* dstp = binned + (size_t)b * BCAP + base;
    for (int i = lane; i < c; i += 64) dstp[i] = srt[ls + i];
  }
}

// ---------------- CSR build, pass 2 (fused): per-bucket node sort + gbase scan
// + cnt/dinv/rowoff + xs (dinv-scaled f16 features, replaces k_xpad/k_bscan) ----
__global__ __launch_bounds__(256) void k_csr(const unsigned* __restrict__ binned,
                                             const int* __restrict__ gcount,
                                             int* __restrict__ rowoff,
                                             int* __restrict__ cnt,
                                             float* __restrict__ dinv,
                                             int* __restrict__ csr,
                                             const float* __restrict__ x,
                                             _Float16* __restrict__ xs) {
  __shared__ int hist[512], offs[512], ps[256], gsc[256];
  __shared__ int sh_gb0;
  __shared__ unsigned srt[BCAP];
  const int b = blockIdx.x, t = threadIdx.x;
  const unsigned* bp = binned + (size_t)b * BCAP;

  // in-block scan of bucket counts -> gb0 (replaces k_bscan)
  int vb = (t < NBUCK) ? gcount[t] : 0;
  gsc[t] = vb;
  __syncthreads();
  for (int off = 1; off < 256; off <<= 1) {
    int a = (t >= off) ? gsc[t - off] : 0;
    __syncthreads();
    gsc[t] += a;
    __syncthreads();
  }
  if (t == b) sh_gb0 = gsc[t] - vb;   // exclusive prefix for this bucket
  hist[t] = 0;
  hist[t + 256] = 0;
  __syncthreads();
  const int gb0 = sh_gb0;
  const int n = min(gcount[b], BCAP);

  for (int i = t; i < n; i += 256) atomicAdd(&hist[bp[i] & 511], 1);
  __syncthreads();
  int e0v = hist[2 * t], e1v = hist[2 * t + 1];
  ps[t] = e0v + e1v;
  __syncthreads();
  for (int off = 1; off < 256; off <<= 1) {
    int a = (t >= off) ? ps[t - off] : 0;
    __syncthreads();
    ps[t] += a;
    __syncthreads();
  }
  int excl = ps[t] - (e0v + e1v);
  offs[2 * t] = excl;
  offs[2 * t + 1] = excl + e0v;
  __syncthreads();
  // per-node outputs
#pragma unroll
  for (int u = 0; u < 2; ++u) {
    int j = 2 * t + u;
    int nd = (b << 9) + j;
    if (nd < N_NODES) {
      int c = hist[j];
      cnt[nd] = c;
      dinv[nd] = rsqrtf((float)(c + 1));
      rowoff[nd] = gb0 + offs[j];
    }
  }
  // xs rows for this bucket's nodes (replaces k_xpad; dinv from hist)
  for (int idx = t; idx < 512 * 24; idx += 256) {
    int j = idx / 24, c = idx - j * 24;
    int nd = (b << 9) + j;
    if (nd < N_NODES) {
      float dv = rsqrtf((float)(hist[j] + 1));
      xs[(size_t)nd * 24 + c] = (_Float16)((c < 21) ? x[(size_t)nd * 21 + c] * dv : 0.f);
    }
  }
  __syncthreads();
  for (int i = t; i < n; i += 256) {
    unsigned p = bp[i];
    int d = p & 511;
    int pos = atomicAdd(&offs[d], 1);
    srt[pos] = p >> 9;
  }
  __syncthreads();
  for (int i = t; i < n; i += 256) csr[gb0 + i] = (int)srt[i];
}

// ---------------- conv1 aggregation: 3 lanes x f16x8 per row, 21 rows/wave ------
__global__ __launch_bounds__(256) void k_aggx(
    const f16x8* __restrict__ xs3, const float* __restrict__ dinv,
    const int* __restrict__ rowoff, const int* __restrict__ cnt,
    const int* __restrict__ csr, float* __restrict__ aggx) {
  int lane = threadIdx.x & 63, wave = threadIdx.x >> 6;
  int j = lane / 3, c = lane - j * 3;
  if (j >= 21) return;
  int i = blockIdx.x * 84 + wave * 21 + j;
  if (i >= N_NODES) return;
  float di = dinv[i];
  int start = rowoff[i], len = cnt[i];
  f16x8 u = xs3[i * 3 + c];
  float a0[8], a1[8], a2[8], a3[8];
#pragma unroll
  for (int t = 0; t < 8; ++t) { a0[t] = (float)u[t]; a1[t] = a2[t] = a3[t] = 0.f; }
  int e = 0;
  for (; e + 3 < len; e += 4) {
    int s0 = csr[start + e], s1 = csr[start + e + 1];
    int s2 = csr[start + e + 2], s3 = csr[start + e + 3];
    f16x8 u0 = xs3[s0 * 3 + c];
    f16x8 u1 = xs3[s1 * 3 + c];
    f16x8 u2 = xs3[s2 * 3 + c];
    f16x8 u3 = xs3[s3 * 3 + c];
#pragma unroll
    for (int t = 0; t < 8; ++t) {
      a0[t] += (float)u0[t]; a1[t] += (float)u1[t];
      a2[t] += (float)u2[t]; a3[t] += (float)u3[t];
    }
  }
  for (; e < len; ++e) {
    int s0 = csr[start + e];
    f16x8 u0 = xs3[s0 * 3 + c];
#pragma unroll
    for (int t = 0; t < 8; ++t) a0[t] += (float)u0[t];
  }
  float4 r0, r1;
  r0.x = di * (a0[0] + a1[0] + a2[0] + a3[0]);
  r0.y = di * (a0[1] + a1[1] + a2[1] + a3[1]);
  r0.z = di * (a0[2] + a1[2] + a2[2] + a3[2]);
  r0.w = di * (a0[3] + a1[3] + a2[3] + a3[3]);
  r1.x = di * (a0[4] + a1[4] + a2[4] + a3[4]);
  r1.y = di * (a0[5] + a1[5] + a2[5] + a3[5]);
  r1.z = di * (a0[6] + a1[6] + a2[6] + a3[6]);
  r1.w = di * (a0[7] + a1[7] + a2[7] + a3[7]);
  *(float4*)(aggx + (size_t)i * 24 + c * 8) = r0;
  *(float4*)(aggx + (size_t)i * 24 + c * 8 + 4) = r1;
}

// ---------------- gemm1: h1 = relu(aggx @ W1 + b1), f16 out ----------------
__global__ __launch_bounds__(256) void k_gemm1(const float4* __restrict__ aggx4,
                                               const float* __restrict__ W1,
                                               const float* __restrict__ b1,
                                               _Float16* __restrict__ h1) {
  __shared__ float As[32][24];
  int t = threadIdx.x;
  int base = blockIdx.x * 32;
  for (int idx = t; idx < 32 * 6; idx += 256) {
    int m = idx / 6, q = idx - m * 6;
    *(float4*)(&As[m][q * 4]) = aggx4[(base + m) * 6 + q];
  }
  float w[21];
#pragma unroll
  for (int k = 0; k < 21; ++k) w[k] = W1[k * 256 + t];
  float bias = b1[t];
  __syncthreads();
  for (int m = 0; m < 32; ++m) {
    float acc = bias;
#pragma unroll
    for (int k = 0; k < 21; ++k) acc = fmaf(As[m][k], w[k], acc);
    h1[(size_t)(base + m) * 256 + t] = (_Float16)fmaxf(acc, 0.f);
  }
}

// ---------------- W prep (merged): transpose + f16 for all three weights -------
// wt2[n*256+k]=W2[k*112+n] (112x256); wt3[n*128+k]=(k<112)?l2w[k*256+n]:0 (256x128);
// wt4[n*256+k]=(n<100)?l3w[k*100+n]:0 (112x256).
__global__ void k_wcvt_all(const float* __restrict__ W2, const float* __restrict__ l2w,
                           const float* __restrict__ l3w, _Float16* __restrict__ wt2,
                           _Float16* __restrict__ wt3, _Float16* __restrict__ wt4) {
  int idx = blockIdx.x * 256 + threadIdx.x;
  const int S1 = 112 * 256, S2 = 256 * 128, S3 = 112 * 256;
  if (idx < S1) {
    int n = idx / 256, k = idx % 256;
    wt2[idx] = (_Float16)W2[k * 112 + n];
  } else if (idx < S1 + S2) {
    int r = idx - S1;
    int n = r / 128, k = r % 128;
    wt3[r] = (_Float16)((k < 112) ? l2w[k * 256 + n] : 0.f);
  } else if (idx < S1 + S2 + S3) {
    int r = idx - S1 - S2;
    int n = r / 256, k = r % 256;
    wt4[r] = (_Float16)((n < 100) ? l3w[k * 100 + n] : 0.f);
  }
}

// ---------------- MFMA GEMM v1: 2-barrier K-loop + A-register-prefetch ----------
template <int K, int KPAD, int NT, int MT, int WR, int WC, int MINW,
          bool BN, bool STATS, bool F16OUT, bool SPLIT>
__global__ __launch_bounds__(256, MINW) void k_mgemm(
    const _Float16* __restrict__ A16, const _Float16* __restrict__ Wt,
    const float* __restrict__ bias, const float* __restrict__ bn_a,
    const float* __restrict__ bn_c, const float* __restrict__ rowscale,
    void* __restrict__ Cv, void* __restrict__ Cv2, int NOUTr,
    float* __restrict__ sums, float* __restrict__ sqs) {
  constexpr int BM = WR * MT * 16;
  constexpr int NR = WC * NT * 16;
  constexpr int BKP = 40;
  constexpr int NC = KPAD / 32;
  constexpr int AIT = BM * 4 / 256;
  constexpr int ABYTES = BM * BKP * 2;
  constexpr int BBYTES = NR * BKP * 2;
  __shared__ __align__(16) char smem[ABYTES + BBYTES];
  _Float16* Ah = (_Float16*)smem;
  _Float16* Bh = (_Float16*)(smem + ABYTES);
  float* C = (float*)Cv;
  _Float16* C16 = (_Float16*)Cv;
  _Float16* C16b = (_Float16*)Cv2;

  const int tid = threadIdx.x;
  const int lane = tid & 63, wave = tid >> 6;
  const int wr = wave % WR, wc = wave / WR;
  const int quad = lane >> 4, ln = lane & 15;
  const int rowbase = blockIdx.x * BM;

  fx4 acc[MT][NT];
#pragma unroll
  for (int mt = 0; mt < MT; ++mt)
#pragma unroll
    for (int j = 0; j < NT; ++j) acc[mt][j] = (fx4){0.f, 0.f, 0.f, 0.f};

  f16x8 pf16[AIT];

  auto loadA = [&](int kc) {
#pragma unroll
    for (int it = 0; it < AIT; ++it) {
      int idx = tid + it * 256;
      int m = idx >> 2, q = idx & 3;
      int gi = rowbase + m;
      int k = kc * 32 + q * 8;
      bool ok = (gi < N_NODES) && (k < K);
      f16x8 z;
#pragma unroll
      for (int t = 0; t < 8; ++t) z[t] = (_Float16)0;
      pf16[it] = ok ? *(const f16x8*)(A16 + (size_t)gi * K + k) : z;
    }
  };

  auto writeA = [&](int kc) {
#pragma unroll
    for (int it = 0; it < AIT; ++it) {
      int idx = tid + it * 256;
      int m = idx >> 2, q = idx & 3;
      int k = kc * 32 + q * 8;
      float vv[8];
#pragma unroll
      for (int t = 0; t < 8; ++t) vv[t] = (float)pf16[it][t];
      if constexpr (BN) {
        if (k < K) {
          float4 a0 = *(const float4*)(bn_a + k);
          float4 a1 = *(const float4*)(bn_a + k + 4);
          float4 c0 = *(const float4*)(bn_c + k);
          float4 c1 = *(const float4*)(bn_c + k + 4);
          float av[8] = {a0.x, a0.y, a0.z, a0.w, a1.x, a1.y, a1.z, a1.w};
          float cv[8] = {c0.x, c0.y, c0.z, c0.w, c1.x, c1.y, c1.z, c1.w};
#pragma unroll
          for (int t = 0; t < 8; ++t) vv[t] = fmaxf(fmaf(vv[t], av[t], cv[t]), 0.f);
        }
      }
      f16x8 hv;
#pragma unroll
      for (int t = 0; t < 8; ++t) hv[t] = (_Float16)vv[t];
      *(f16x8*)(Ah + m * BKP + q * 8) = hv;
    }
  };

  loadA(0);
  for (int kc = 0; kc < NC; ++kc) {
    __syncthreads();
    writeA(kc);
    for (int idx = tid; idx < NR * 4; idx += 256) {
      int n = idx >> 2, p = idx & 3;
      *(f16x8*)(Bh + n * BKP + p * 8) =
          *(const f16x8*)(Wt + n * KPAD + kc * 32 + p * 8);
    }
    __syncthreads();
    if (kc + 1 < NC) loadA(kc + 1);
    f16x8 nf[MT];
#pragma unroll
    for (int mt = 0; mt < MT; ++mt) {
      int r = (wr * MT + mt) * 16 + ln;
      nf[mt] = *(const f16x8*)(Ah + r * BKP + quad * 8);
    }
#pragma unroll
    for (int j = 0; j < NT; ++j) {
      int n = (wc * NT + j) * 16 + ln;
      f16x8 wh = *(const f16x8*)(Bh + n * BKP + quad * 8);
#pragma unroll
      for (int mt = 0; mt < MT; ++mt)
        acc[mt][j] = __builtin_amdgcn_mfma_f32_16x16x32_f16(wh, nf[mt], acc[mt][j], 0, 0, 0);
    }
  }

  float* s_s = (float*)smem;
  float* s_q = s_s + NR;
  __syncthreads();
  if constexpr (STATS) {
    for (int c = tid; c < 2 * NR; c += 256) s_s[c] = 0.f;
    __syncthreads();
  }
  float rs[MT];
#pragma unroll
  for (int mt = 0; mt < MT; ++mt) {
    int nd = rowbase + (wr * MT + mt) * 16 + ln;
    rs[mt] = (rowscale != nullptr && nd < N_NODES) ? rowscale[nd] : 1.f;
  }
#pragma unroll
  for (int j = 0; j < NT; ++j) {
    int ch0 = (wc * NT + j) * 16 + quad * 4;
    bool cv = ch0 < NOUTr;
    float4 b4 = make_float4(0.f, 0.f, 0.f, 0.f);
    if (cv && bias != nullptr) b4 = *(const float4*)(bias + ch0);
    float sc[4] = {0.f, 0.f, 0.f, 0.f}, sq[4] = {0.f, 0.f, 0.f, 0.f};
#pragma unroll
    for (int mt = 0; mt < MT; ++mt) {
      int nd = rowbase + (wr * MT + mt) * 16 + ln;
      if (nd < N_NODES && cv) {
        float v0 = (acc[mt][j][0] + b4.x) * rs[mt];
        float v1 = (acc[mt][j][1] + b4.y) * rs[mt];
        float v2 = (acc[mt][j][2] + b4.z) * rs[mt];
        float v3 = (acc[mt][j][3] + b4.w) * rs[mt];
        if constexpr (F16OUT) {
          f16x4 o = {(_Float16)v0, (_Float16)v1, (_Float16)v2, (_Float16)v3};
          if constexpr (SPLIT) {
            _Float16* dp = (ch0 < 56)
                ? C16 + (size_t)nd * 64 + ch0
                : C16b + (size_t)nd * 64 + (ch0 - 56);
            *(f16x4*)dp = o;
          } else {
            *(f16x4*)(C16 + (size_t)nd * NOUTr + ch0) = o;
          }
        } else {
          float4 o = make_float4(v0, v1, v2, v3);
          *(float4*)(C + (size_t)nd * NOUTr + ch0) = o;
        }
        if constexpr (STATS) {
          sc[0] += v0; sq[0] = fmaf(v0, v0, sq[0]);
          sc[1] += v1; sq[1] = fmaf(v1, v1, sq[1]);
          sc[2] += v2; sq[2] = fmaf(v2, v2, sq[2]);
          sc[3] += v3; sq[3] = fmaf(v3, v3, sq[3]);
        }
      }
    }
    if constexpr (STATS) {
      if (cv) {
#pragma unroll
        for (int r = 0; r < 4; ++r) {
          float s = sc[r], q = sq[r];
          s += __shfl_xor(s, 1); q += __shfl_xor(q, 1);
          s += __shfl_xor(s, 2); q += __shfl_xor(q, 2);
          s += __shfl_xor(s, 4); q += __shfl_xor(q, 4);
          s += __shfl_xor(s, 8); q += __shfl_xor(q, 8);
          if (ln == 0) {
            atomicAdd(&s_s[ch0 + r], s);
            atomicAdd(&s_q[ch0 + r], q);
          }
        }
      }
    }
  }
  if constexpr (STATS) {
    __syncthreads();
    int rep = (blockIdx.x & (NREP - 1));
    for (int c = tid; c < NR; c += 256) {
      if (c < NOUTr) {
        atomicAdd(&sums[rep * NOUTr + c], s_s[c]);
        atomicAdd(&sqs[rep * NOUTr + c], s_q[c]);
      }
    }
  }
}

// ---------------- MFMA GEMM v2: B-resident LDS, barrier-free K-loop -------------
template <int K, int KPAD, int NT, int MT, int MINW,
          bool BN, bool STATS, bool F16OUT>
__global__ __launch_bounds__(256, MINW) void k_mgemm2(
    const _Float16* __restrict__ A16, const _Float16* __restrict__ Wt,
    const float* __restrict__ bias, const float* __restrict__ bn_a,
    const float* __restrict__ bn_c, const float* __restrict__ rowscale,
    void* __restrict__ Cv, int NOUTr, float* __restrict__ sums,
    float* __restrict__ sqs) {
  constexpr int WR = 4;
  constexpr int BM = WR * MT * 16;
  constexpr int NR = NT * 16;
  constexpr int KPS = KPAD + 8;
  constexpr int NC = KPAD / 32;
  __shared__ __align__(16) _Float16 Bh[NR * KPS];

  const int tid = threadIdx.x;
  const int lane = tid & 63, wave = tid >> 6;
  const int quad = lane >> 4, ln = lane & 15;
  const int rowbase = blockIdx.x * BM;
  const int chbase = blockIdx.y * NR;

  for (int idx = tid; idx < NR * (KPAD / 8); idx += 256) {
    int n = idx / (KPAD / 8), p = idx % (KPAD / 8);
    *(f16x8*)(Bh + n * KPS + p * 8) =
        *(const f16x8*)(Wt + (size_t)(chbase + n) * KPAD + p * 8);
  }
  __syncthreads();

  fx4 acc[MT][NT];
#pragma unroll
  for (int mt = 0; mt < MT; ++mt)
#pragma unroll
    for (int j = 0; j < NT; ++j) acc[mt][j] = (fx4){0.f, 0.f, 0.f, 0.f};

  for (int kc = 0; kc < NC; ++kc) {
    const int k0 = kc * 32 + quad * 8;
    f16x8 af[MT];
#pragma unroll
    for (int mt = 0; mt < MT; ++mt) {
      int gi = rowbase + (wave * MT + mt) * 16 + ln;
      bool ok = (gi < N_NODES) && (k0 < K);
      f16x8 z;
#pragma unroll
      for (int t = 0; t < 8; ++t) z[t] = (_Float16)0;
      af[mt] = ok ? *(const f16x8*)(A16 + (size_t)gi * K + k0) : z;
    }
    if constexpr (BN) {
      if (k0 < K) {
        float4 ba0 = *(const float4*)(bn_a + k0);
        float4 ba1 = *(const float4*)(bn_a + k0 + 4);
        float4 bc0 = *(const float4*)(bn_c + k0);
        float4 bc1 = *(const float4*)(bn_c + k0 + 4);
        float av[8] = {ba0.x, ba0.y, ba0.z, ba0.w, ba1.x, ba1.y, ba1.z, ba1.w};
        float cv[8] = {bc0.x, bc0.y, bc0.z, bc0.w, bc1.x, bc1.y, bc1.z, bc1.w};
#pragma unroll
        for (int mt = 0; mt < MT; ++mt)
#pragma unroll
          for (int t = 0; t < 8; ++t)
            af[mt][t] = (_Float16)fmaxf(fmaf((float)af[mt][t], av[t], cv[t]), 0.f);
      }
    }
#pragma unroll
    for (int j = 0; j < NT; ++j) {
      f16x8 wh = *(const f16x8*)(Bh + (j * 16 + ln) * KPS + kc * 32 + quad * 8);
#pragma unroll
      for (int mt = 0; mt < MT; ++mt)
        acc[mt][j] = __builtin_amdgcn_mfma_f32_16x16x32_f16(wh, af[mt], acc[mt][j], 0, 0, 0);
    }
  }

  float* s_s = (float*)Bh;
  float* s_q = s_s + NR;
  __syncthreads();
  if constexpr (STATS) {
    for (int c = tid; c < 2 * NR; c += 256) s_s[c] = 0.f;
    __syncthreads();
  }
  float rs[MT];
#pragma unroll
  for (int mt = 0; mt < MT; ++mt) {
    int nd = rowbase + (wave * MT + mt) * 16 + ln;
    rs[mt] = (rowscale != nullptr && nd < N_NODES) ? rowscale[nd] : 1.f;
  }
  float* C = (float*)Cv;
  _Float16* C16 = (_Float16*)Cv;
#pragma unroll
  for (int j = 0; j < NT; ++j) {
    int lch = j * 16 + quad * 4;
    int ch0 = chbase + lch;
    bool cv = ch0 < NOUTr;
    float4 b4 = make_float4(0.f, 0.f, 0.f, 0.f);
    if (cv && bias != nullptr) b4 = *(const float4*)(bias + ch0);
    float sc[4] = {0.f, 0.f, 0.f, 0.f}, sq[4] = {0.f, 0.f, 0.f, 0.f};
#pragma unroll
    for (int mt = 0; mt < MT; ++mt) {
      int nd = rowbase + (wave * MT + mt) * 16 + ln;
      if (nd < N_NODES && cv) {
        float v0 = (acc[mt][j][0] + b4.x) * rs[mt];
        float v1 = (acc[mt][j][1] + b4.y) * rs[mt];
        float v2 = (acc[mt][j][2] + b4.z) * rs[mt];
        float v3 = (acc[mt][j][3] + b4.w) * rs[mt];
        if constexpr (F16OUT) {
          f16x4 o = {(_Float16)v0, (_Float16)v1, (_Float16)v2, (_Float16)v3};
          *(f16x4*)(C16 + (size_t)nd * NOUTr + ch0) = o;
        } else {
          float4 o = make_float4(v0, v1, v2, v3);
          *(float4*)(C + (size_t)nd * NOUTr + ch0) = o;
        }
        if constexpr (STATS) {
          sc[0] += v0; sq[0] = fmaf(v0, v0, sq[0]);
          sc[1] += v1; sq[1] = fmaf(v1, v1, sq[1]);
          sc[2] += v2; sq[2] = fmaf(v2, v2, sq[2]);
          sc[3] += v3; sq[3] = fmaf(v3, v3, sq[3]);
        }
      }
    }
    if constexpr (STATS) {
      if (cv) {
#pragma unroll
        for (int r = 0; r < 4; ++r) {
          float s = sc[r], q = sq[r];
          s += __shfl_xor(s, 1); q += __shfl_xor(q, 1);
          s += __shfl_xor(s, 2); q += __shfl_xor(q, 2);
          s += __shfl_xor(s, 4); q += __shfl_xor(q, 4);
          s += __shfl_xor(s, 8); q += __shfl_xor(q, 8);
          if (ln == 0) {
            atomicAdd(&s_s[lch + r], s);
            atomicAdd(&s_q[lch + r], q);
          }
        }
      }
    }
  }
  if constexpr (STATS) {
    __syncthreads();
    int rep = (blockIdx.x & (NREP - 1));
    for (int c = tid; c < NR; c += 256) {
      int gc = chbase + c;
      if (gc < NOUTr) {
        atomicAdd(&sums[rep * NOUTr + gc], s_s[c]);
        atomicAdd(&sqs[rep * NOUTr + gc], s_q[c]);
      }
    }
  }
}

// ---------------- conv2 aggregation, half-channel pass + fused g2 stats ---------
// Stats of g2 (this pass's 56 channels) computed in-kernel: shfl-reduce over the
// 8 nodes per wave -> LDS partials -> NREP-spread global atomics. Replaces the
// standalone k_colstats16<112> pass (22 MB re-read + 1 launch).
__global__ __launch_bounds__(256) void k_agg2(
    const f16x8* __restrict__ t2x8, const float* __restrict__ dinv,
    const int* __restrict__ rowoff, const int* __restrict__ cnt,
    const int* __restrict__ csr, const float* __restrict__ b2,
    _Float16* __restrict__ g2, int off, float* __restrict__ sums,
    float* __restrict__ sqs) {
  __shared__ float s_s[56], s_q[56];
  int tid = threadIdx.x;
  int lane = tid & 63, wave = tid >> 6;
  int j = lane >> 3, c = lane & 7;
  int i = blockIdx.x * 32 + wave * 8 + j;      // 3125*32 == 100000 exactly
  if (tid < 56) { s_s[tid] = 0.f; s_q[tid] = 0.f; }
  float di = dinv[i];
  int start = rowoff[i], len = cnt[i];
  f16x8 u = t2x8[i * 8 + c];
  float a0[8], a1[8], a2[8], a3[8];
#pragma unroll
  for (int t = 0; t < 8; ++t) { a0[t] = (float)u[t]; a1[t] = a2[t] = a3[t] = 0.f; }
  int e = 0;
  for (; e + 3 < len; e += 4) {
    int s0 = csr[start + e], s1 = csr[start + e + 1];
    int s2 = csr[start + e + 2], s3 = csr[start + e + 3];
    f16x8 u0 = t2x8[s0 * 8 + c];
    f16x8 u1 = t2x8[s1 * 8 + c];
    f16x8 u2 = t2x8[s2 * 8 + c];
    f16x8 u3 = t2x8[s3 * 8 + c];
#pragma unroll
    for (int t = 0; t < 8; ++t) {
      a0[t] += (float)u0[t]; a1[t] += (float)u1[t];
      a2[t] += (float)u2[t]; a3[t] += (float)u3[t];
    }
  }
  for (; e < len; ++e) {
    int s0 = csr[start + e];
    f16x8 u0 = t2x8[s0 * 8 + c];
#pragma unroll
    for (int t = 0; t < 8; ++t) a0[t] += (float)u0[t];
  }
  float ov[8];
  {
    float4 blo = *(const float4*)(b2 + off + c * 8);
    float4 bhi = *(const float4*)(b2 + off + c * 8 + 4);
    float bb[8] = {blo.x, blo.y, blo.z, blo.w, bhi.x, bhi.y, bhi.z, bhi.w};
    f16x8 o;
#pragma unroll
    for (int t = 0; t < 8; ++t) {
      ov[t] = fmaf(di, a0[t] + a1[t] + a2[t] + a3[t], bb[t]);
      o[t] = (_Float16)ov[t];
    }
    if (c < 7) *(f16x8*)(g2 + (size_t)i * 112 + off + c * 8) = o;
  }
  __syncthreads();   // s_s/s_q zeroed
  // reduce over the 8 nodes in this wave (lanes differing in bits 3..5)
#pragma unroll
  for (int t = 0; t < 8; ++t) {
    float s = (c < 7) ? ov[t] : 0.f;
    float q = (c < 7) ? ov[t] * ov[t] : 0.f;
    s += __shfl_xor(s, 8);  q += __shfl_xor(q, 8);
    s += __shfl_xor(s, 16); q += __shfl_xor(q, 16);
    s += __shfl_xor(s, 32); q += __shfl_xor(q, 32);
    if (j == 0 && c < 7) {
      atomicAdd(&s_s[c * 8 + t], s);
      atomicAdd(&s_q[c * 8 + t], q);
    }
  }
  __syncthreads();
  int rep = (blockIdx.x & (NREP - 1));
  if (tid < 56) {
    atomicAdd(&sums[rep * 112 + off + tid], s_s[tid]);
    atomicAdd(&sqs[rep * 112 + off + tid], s_q[tid]);
  }
}

template <int C>
__global__ void k_bnfinal(const float* __restrict__ sums, const float* __restrict__ sqs,
                          const float* __restrict__ gamma, const float* __restrict__ beta,
                          float* __restrict__ bn_a, float* __restrict__ bn_c) {
  int c = threadIdx.x;
  if (c >= C) return;
  float s = 0.f, q = 0.f;
#pragma unroll
  for (int r = 0; r < NREP; ++r) {
    s += sums[r * C + c];
    q += sqs[r * C + c];
  }
  const float inv_n = 1.0f / (float)N_NODES;
  float mean = s * inv_n;
  float var = fmaxf(q * inv_n - mean * mean, 0.f);
  float rstd = 1.0f / sqrtf(var + 1e-5f);
  float a = gamma[c] * rstd;
  bn_a[c] = a;
  bn_c[c] = beta[c] - mean * a;
}

// ---------------- final (f16 h4) ----------------
__global__ void k_final(const _Float16* __restrict__ h4, const float* __restrict__ bn_a,
                        const float* __restrict__ bn_c, const float* __restrict__ w4,
                        const float* __restrict__ b4, float* __restrict__ out) {
  int lane = threadIdx.x & 63;
  int i = blockIdx.x * 4 + (threadIdx.x >> 6);
  float acc = fmaxf(fmaf((float)h4[(size_t)i * 100 + lane], bn_a[lane], bn_c[lane]), 0.f) * w4[lane];
  if (lane < 36) {
    int k = lane + 64;
    acc += fmaxf(fmaf((float)h4[(size_t)i * 100 + k], bn_a[k], bn_c[k]), 0.f) * w4[k];
  }
#pragma unroll
  for (int off = 32; off >= 1; off >>= 1) acc += __shfl_down(acc, off);
  if (lane == 0) out[i] = acc + b4[0];
}

extern "C" void kernel_launch(void* const* d_in, const int* in_sizes, int n_in,
                              void* d_out, int out_size, void* d_ws, size_t ws_size,
                              hipStream_t stream) {
  const float* x   = (const float*)d_in[0];
  const int*   ei  = (const int*)d_in[1];
  const float* W1  = (const float*)d_in[2];
  const float* b1  = (const float*)d_in[3];
  const float* W2  = (const float*)d_in[4];
  const float* b2  = (const float*)d_in[5];
  const float* l2w = (const float*)d_in[6];
  const float* l2b = (const float*)d_in[7];
  const float* l3w = (const float*)d_in[8];
  const float* l3b = (const float*)d_in[9];
  const float* l4w = (const float*)d_in[10];
  const float* l4b = (const float*)d_in[11];
  const float* g1  = (const float*)d_in[12];
  const float* be1 = (const float*)d_in[13];
  const float* g2w = (const float*)d_in[14];
  const float* be2 = (const float*)d_in[15];
  const float* g3  = (const float*)d_in[16];
  const float* be3 = (const float*)d_in[17];
  float* out = (float*)d_out;

  char* base = (char*)d_ws;
  size_t off = 0;
  auto alloc = [&](size_t bytes) -> char* {
    char* p = base + off;
    off = (off + bytes + 255) & ~(size_t)255;
    return p;
  };
  int*   cnt    = (int*)alloc((size_t)N_NODES * 4);
  int*   rowoff = (int*)alloc((size_t)N_NODES * 4);
  float* dinv   = (float*)alloc((size_t)N_NODES * 4);
  int*   csr    = (int*)alloc((size_t)N_EDGES * 4);
  unsigned* binned = (unsigned*)alloc((size_t)NBUCK * BCAP * 4);
  int*   gcount = (int*)alloc(NBUCK * 4);
  float* stats  = (float*)alloc((size_t)NREP * 960 * 4);
  float* bnco   = (float*)alloc(960 * 4);
  _Float16* xs  = (_Float16*)alloc((size_t)N_NODES * 24 * 2);
  float* aggx   = (float*)alloc((size_t)N_NODES * 24 * 4);
  _Float16* h1  = (_Float16*)alloc((size_t)N_NODES * 256 * 2);  // f16; reused as h3
  _Float16* t2a = (_Float16*)alloc((size_t)N_NODES * 64 * 2);   // split ch 0-55 (+pad)
  _Float16* t2b = (_Float16*)alloc((size_t)N_NODES * 64 * 2);   // split ch 56-111 (+pad)
  _Float16* g2h = (_Float16*)alloc((size_t)N_NODES * 112 * 2);  // f16 conv2 output
  _Float16* h4  = (_Float16*)alloc((size_t)N_NODES * 112 * 2);  // f16 h4
  _Float16* wt2 = (_Float16*)alloc(112 * 256 * 2);
  _Float16* wt3 = (_Float16*)alloc(256 * 128 * 2);
  _Float16* wt4 = (_Float16*)alloc(112 * 256 * 2);

  float* sums1 = stats;
  float* sqs1  = sums1 + NREP * 112;
  float* sums2 = sqs1 + NREP * 112;
  float* sqs2  = sums2 + NREP * 256;
  float* sums3 = sqs2 + NREP * 256;
  float* sqs3  = sums3 + NREP * 112;
  float* bn_a1 = bnco + 0,   *bn_c1 = bnco + 112;
  float* bn_a2 = bnco + 224, *bn_c2 = bnco + 480;
  float* bn_a3 = bnco + 736, *bn_c3 = bnco + 848;

  hipMemsetAsync(gcount, 0, NBUCK * 4, stream);
  hipMemsetAsync(stats, 0, (size_t)NREP * 960 * 4, stream);

  k_bin<<<NBUCK, 256, 0, stream>>>(ei, binned, gcount);
  k_csr<<<NBUCK, 256, 0, stream>>>(binned, gcount, rowoff, cnt, dinv, csr, x, xs);

  k_wcvt_all<<<352, 256, 0, stream>>>(W2, l2w, l3w, wt2, wt3, wt4);

  k_aggx<<<(N_NODES + 83) / 84, 256, 0, stream>>>((const f16x8*)xs, dinv, rowoff,
                                                  cnt, csr, aggx);
  k_gemm1<<<3125, 256, 0, stream>>>((const float4*)aggx, W1, b1, h1);

  // t2 = dinv*(h1@W2) f16 split: v1 pipelined, 25.6 KB LDS
  k_mgemm<256, 256, 7, 2, 4, 1, 4, false, false, true, true>
      <<<782, 256, 0, stream>>>(h1, wt2, nullptr, nullptr, nullptr, dinv,
                                t2a, t2b, 112, nullptr, nullptr);
  k_agg2<<<3125, 256, 0, stream>>>((const f16x8*)t2a, dinv, rowoff, cnt, csr, b2,
                                   g2h, 0, sums1, sqs1);
  k_agg2<<<3125, 256, 0, stream>>>((const f16x8*)t2b, dinv, rowoff, cnt, csr, b2,
                                   g2h, 56, sums1, sqs1);
  k_bnfinal<112><<<1, 128, 0, stream>>>(sums1, sqs1, g1, be1, bn_a1, bn_c1);

  // h3 = relu(bn1(g2))@lin2_w + b: v2 barrier-free, 2 y-tiles
  k_mgemm2<112, 128, 8, 2, 3, true, true, true>
      <<<dim3(782, 2), 256, 0, stream>>>(g2h, wt3, l2b, bn_a1, bn_c1, nullptr,
                                         h1, 256, sums2, sqs2);
  k_bnfinal<256><<<1, 256, 0, stream>>>(sums2, sqs2, g2w, be2, bn_a2, bn_c2);

  // h4 = relu(bn2(h3))@lin3_w + b: v1 pipelined, f16-out
  k_mgemm<256, 256, 7, 2, 4, 1, 4, true, true, true, false>
      <<<782, 256, 0, stream>>>(h1, wt4, l3b, bn_a2, bn_c2, nullptr,
                                h4, nullptr, 100, sums3, sqs3);
  k_bnfinal<100><<<1, 128, 0, stream>>>(sums3, sqs3, g3, be3, bn_a3, bn_c3);

  k_final<<<25000, 256, 0, stream>>>(h4, bn_a3, bn_c3, l4w, l4b, out);
}

// Round 14
// 409.765 us; speedup vs baseline: 1.0510x; 1.0510x over previous
//
#include <hip/hip_runtime.h>

#define N_NODES 100000
#define N_EDGES 1600000

typedef _Float16 f16x8 __attribute__((ext_vector_type(8)));
typedef _Float16 f16x4 __attribute__((ext_vector_type(4)));
typedef float fx4 __attribute__((ext_vector_type(4)));

#define NREP 16     // stats-accumulator replication to de-contend atomics
#define NBUCK 196   // ceil(100000/512) buckets of 512 nodes
#define CHUNK 8192  // edges per k_bin block
#define BCAP 12288  // per-bucket slot capacity

// ---------------- CSR build, pass 1: LDS counting-sort chunks by bucket --------
__global__ __launch_bounds__(256) void k_bin(const int* __restrict__ ei,
                                             unsigned* __restrict__ binned,
                                             int* __restrict__ gcount) {
  __shared__ unsigned pr[CHUNK];
  __shared__ unsigned srt[CHUNK];
  __shared__ unsigned char bk[CHUNK];
  __shared__ int hist[256], scanb[256], offs[256], bs[256], gb[256];
  const int t = threadIdx.x;
  const int e0 = blockIdx.x * CHUNK;
  const int n = min(CHUNK, N_EDGES - e0);
  hist[t] = 0;
  __syncthreads();
  for (int i = t; i < n; i += 256) {
    int src = ei[e0 + i], dst = ei[N_EDGES + e0 + i];
    int b = dst >> 9;
    pr[i] = ((unsigned)src << 9) | (unsigned)(dst & 511);
    bk[i] = (unsigned char)b;
    atomicAdd(&hist[b], 1);
  }
  __syncthreads();
  int v = hist[t];
  scanb[t] = v;
  __syncthreads();
  for (int off = 1; off < 256; off <<= 1) {
    int a = (t >= off) ? scanb[t - off] : 0;
    __syncthreads();
    scanb[t] += a;
    __syncthreads();
  }
  offs[t] = scanb[t] - v;
  bs[t] = scanb[t] - v;
  __syncthreads();
  for (int i = t; i < n; i += 256) {
    int b = bk[i];
    int p = atomicAdd(&offs[b], 1);
    srt[p] = pr[i];
  }
  if (t < NBUCK && v > 0) gb[t] = atomicAdd(&gcount[t], v);
  __syncthreads();
  int wave = t >> 6, lane = t & 63;
  for (int b = wave; b < NBUCK; b += 4) {
    int c = hist[b];
    if (c == 0) continue;
    int ls = bs[b], base = gb[b];
    unsigned* dstp = binned + (size_t)b * BCAP + base;
    for (int i = lane; i < c; i += 64) dstp[i] = srt[ls + i];
  }
}

__global__ void k_bscan(const int* __restrict__ gcount, int* __restrict__ gbase) {
  __shared__ int s[256];
  int t = threadIdx.x;
  int v = (t < NBUCK) ? gcount[t] : 0;
  s[t] = v;
  __syncthreads();
  for (int off = 1; off < 256; off <<= 1) {
    int a = (t >= off) ? s[t - off] : 0;
    __syncthreads();
    s[t] += a;
    __syncthreads();
  }
  if (t < NBUCK) gbase[t] = s[t] - v;
}

__global__ __launch_bounds__(256) void k_csr(const unsigned* __restrict__ binned,
                                             const int* __restrict__ gcount,
                                             const int* __restrict__ gbase,
                                             int* __restrict__ rowoff,
                                             int* __restrict__ cnt,
                                             float* __restrict__ dinv,
                                             int* __restrict__ csr) {
  __shared__ int hist[512], offs[512], ps[256];
  __shared__ unsigned srt[BCAP];
  const int b = blockIdx.x, t = threadIdx.x;
  const int n = min(gcount[b], BCAP);
  const int gb0 = gbase[b];
  const unsigned* bp = binned + (size_t)b * BCAP;
  hist[t] = 0;
  hist[t + 256] = 0;
  __syncthreads();
  for (int i = t; i < n; i += 256) atomicAdd(&hist[bp[i] & 511], 1);
  __syncthreads();
  int e0v = hist[2 * t], e1v = hist[2 * t + 1];
  ps[t] = e0v + e1v;
  __syncthreads();
  for (int off = 1; off < 256; off <<= 1) {
    int a = (t >= off) ? ps[t - off] : 0;
    __syncthreads();
    ps[t] += a;
    __syncthreads();
  }
  int excl = ps[t] - (e0v + e1v);
  offs[2 * t] = excl;
  offs[2 * t + 1] = excl + e0v;
  __syncthreads();
#pragma unroll
  for (int u = 0; u < 2; ++u) {
    int j = 2 * t + u;
    int nd = (b << 9) + j;
    if (nd < N_NODES) {
      int c = hist[j];
      cnt[nd] = c;
      dinv[nd] = rsqrtf((float)(c + 1));
      rowoff[nd] = gb0 + offs[j];
    }
  }
  __syncthreads();
  for (int i = t; i < n; i += 256) {
    unsigned p = bp[i];
    int d = p & 511;
    int pos = atomicAdd(&offs[d], 1);
    srt[pos] = p >> 9;
  }
  __syncthreads();
  for (int i = t; i < n; i += 256) csr[gb0 + i] = (int)srt[i];
}

// ---------------- xs = dinv[i] * x[i], f16, padded [N,24] ----------------
__global__ void k_xpad(const float* __restrict__ x, const float* __restrict__ dinv,
                       _Float16* __restrict__ xs) {
  int idx = blockIdx.x * 256 + threadIdx.x;
  if (idx >= N_NODES * 24) return;
  int r = idx / 24, c = idx - r * 24;
  xs[idx] = (_Float16)((c < 21) ? x[r * 21 + c] * dinv[r] : 0.f);
}

// ---------------- conv1 aggregation: 3 lanes x f16x8 per row, 21 rows/wave ------
__global__ __launch_bounds__(256) void k_aggx(
    const f16x8* __restrict__ xs3, const float* __restrict__ dinv,
    const int* __restrict__ rowoff, const int* __restrict__ cnt,
    const int* __restrict__ csr, float* __restrict__ aggx) {
  int lane = threadIdx.x & 63, wave = threadIdx.x >> 6;
  int j = lane / 3, c = lane - j * 3;
  if (j >= 21) return;
  int i = blockIdx.x * 84 + wave * 21 + j;
  if (i >= N_NODES) return;
  float di = dinv[i];
  int start = rowoff[i], len = cnt[i];
  f16x8 u = xs3[i * 3 + c];
  float a0[8], a1[8], a2[8], a3[8];
#pragma unroll
  for (int t = 0; t < 8; ++t) { a0[t] = (float)u[t]; a1[t] = a2[t] = a3[t] = 0.f; }
  int e = 0;
  for (; e + 3 < len; e += 4) {
    int s0 = csr[start + e], s1 = csr[start + e + 1];
    int s2 = csr[start + e + 2], s3 = csr[start + e + 3];
    f16x8 u0 = xs3[s0 * 3 + c];
    f16x8 u1 = xs3[s1 * 3 + c];
    f16x8 u2 = xs3[s2 * 3 + c];
    f16x8 u3 = xs3[s3 * 3 + c];
#pragma unroll
    for (int t = 0; t < 8; ++t) {
      a0[t] += (float)u0[t]; a1[t] += (float)u1[t];
      a2[t] += (float)u2[t]; a3[t] += (float)u3[t];
    }
  }
  for (; e < len; ++e) {
    int s0 = csr[start + e];
    f16x8 u0 = xs3[s0 * 3 + c];
#pragma unroll
    for (int t = 0; t < 8; ++t) a0[t] += (float)u0[t];
  }
  float4 r0, r1;
  r0.x = di * (a0[0] + a1[0] + a2[0] + a3[0]);
  r0.y = di * (a0[1] + a1[1] + a2[1] + a3[1]);
  r0.z = di * (a0[2] + a1[2] + a2[2] + a3[2]);
  r0.w = di * (a0[3] + a1[3] + a2[3] + a3[3]);
  r1.x = di * (a0[4] + a1[4] + a2[4] + a3[4]);
  r1.y = di * (a0[5] + a1[5] + a2[5] + a3[5]);
  r1.z = di * (a0[6] + a1[6] + a2[6] + a3[6]);
  r1.w = di * (a0[7] + a1[7] + a2[7] + a3[7]);
  *(float4*)(aggx + (size_t)i * 24 + c * 8) = r0;
  *(float4*)(aggx + (size_t)i * 24 + c * 8 + 4) = r1;
}

// ---------------- gemm1: h1 = relu(aggx @ W1 + b1), f16 out ----------------
__global__ __launch_bounds__(256) void k_gemm1(const float4* __restrict__ aggx4,
                                               const float* __restrict__ W1,
                                               const float* __restrict__ b1,
                                               _Float16* __restrict__ h1) {
  __shared__ float As[32][24];
  int t = threadIdx.x;
  int base = blockIdx.x * 32;
  for (int idx = t; idx < 32 * 6; idx += 256) {
    int m = idx / 6, q = idx - m * 6;
    *(float4*)(&As[m][q * 4]) = aggx4[(base + m) * 6 + q];
  }
  float w[21];
#pragma unroll
  for (int k = 0; k < 21; ++k) w[k] = W1[k * 256 + t];
  float bias = b1[t];
  __syncthreads();
  for (int m = 0; m < 32; ++m) {
    float acc = bias;
#pragma unroll
    for (int k = 0; k < 21; ++k) acc = fmaf(As[m][k], w[k], acc);
    h1[(size_t)(base + m) * 256 + t] = (_Float16)fmaxf(acc, 0.f);
  }
}

// ---------------- W prep: transpose + f16 ----------------
template <int K, int KPAD, int NOUT, int NR>
__global__ void k_wcvt(const float* __restrict__ W, _Float16* __restrict__ Wh) {
  int idx = blockIdx.x * 256 + threadIdx.x;
  if (idx >= NR * KPAD) return;
  int n = idx / KPAD, k = idx % KPAD;
  float v = (n < NOUT && k < K) ? W[k * NOUT + n] : 0.f;
  Wh[idx] = (_Float16)v;
}

// ---------------- MFMA GEMM v1: 2-barrier K-loop + A-register-prefetch ----------
// (Measured best for K=256 cases: 25.6 KB LDS -> 4 blocks/CU.)
template <int K, int KPAD, int NT, int MT, int WR, int WC, int MINW,
          bool BN, bool STATS, bool F16OUT, bool SPLIT>
__global__ __launch_bounds__(256, MINW) void k_mgemm(
    const _Float16* __restrict__ A16, const _Float16* __restrict__ Wt,
    const float* __restrict__ bias, const float* __restrict__ bn_a,
    const float* __restrict__ bn_c, const float* __restrict__ rowscale,
    void* __restrict__ Cv, void* __restrict__ Cv2, int NOUTr,
    float* __restrict__ sums, float* __restrict__ sqs) {
  constexpr int BM = WR * MT * 16;
  constexpr int NR = WC * NT * 16;
  constexpr int BKP = 40;
  constexpr int NC = KPAD / 32;
  constexpr int AIT = BM * 4 / 256;
  constexpr int ABYTES = BM * BKP * 2;
  constexpr int BBYTES = NR * BKP * 2;
  __shared__ __align__(16) char smem[ABYTES + BBYTES];
  _Float16* Ah = (_Float16*)smem;
  _Float16* Bh = (_Float16*)(smem + ABYTES);
  float* C = (float*)Cv;
  _Float16* C16 = (_Float16*)Cv;
  _Float16* C16b = (_Float16*)Cv2;

  const int tid = threadIdx.x;
  const int lane = tid & 63, wave = tid >> 6;
  const int wr = wave % WR, wc = wave / WR;
  const int quad = lane >> 4, ln = lane & 15;
  const int rowbase = blockIdx.x * BM;

  fx4 acc[MT][NT];
#pragma unroll
  for (int mt = 0; mt < MT; ++mt)
#pragma unroll
    for (int j = 0; j < NT; ++j) acc[mt][j] = (fx4){0.f, 0.f, 0.f, 0.f};

  f16x8 pf16[AIT];

  auto loadA = [&](int kc) {
#pragma unroll
    for (int it = 0; it < AIT; ++it) {
      int idx = tid + it * 256;
      int m = idx >> 2, q = idx & 3;
      int gi = rowbase + m;
      int k = kc * 32 + q * 8;
      bool ok = (gi < N_NODES) && (k < K);
      f16x8 z;
#pragma unroll
      for (int t = 0; t < 8; ++t) z[t] = (_Float16)0;
      pf16[it] = ok ? *(const f16x8*)(A16 + (size_t)gi * K + k) : z;
    }
  };

  auto writeA = [&](int kc) {
#pragma unroll
    for (int it = 0; it < AIT; ++it) {
      int idx = tid + it * 256;
      int m = idx >> 2, q = idx & 3;
      int k = kc * 32 + q * 8;
      float vv[8];
#pragma unroll
      for (int t = 0; t < 8; ++t) vv[t] = (float)pf16[it][t];
      if constexpr (BN) {
        if (k < K) {
          float4 a0 = *(const float4*)(bn_a + k);
          float4 a1 = *(const float4*)(bn_a + k + 4);
          float4 c0 = *(const float4*)(bn_c + k);
          float4 c1 = *(const float4*)(bn_c + k + 4);
          float av[8] = {a0.x, a0.y, a0.z, a0.w, a1.x, a1.y, a1.z, a1.w};
          float cv[8] = {c0.x, c0.y, c0.z, c0.w, c1.x, c1.y, c1.z, c1.w};
#pragma unroll
          for (int t = 0; t < 8; ++t) vv[t] = fmaxf(fmaf(vv[t], av[t], cv[t]), 0.f);
        }
      }
      f16x8 hv;
#pragma unroll
      for (int t = 0; t < 8; ++t) hv[t] = (_Float16)vv[t];
      *(f16x8*)(Ah + m * BKP + q * 8) = hv;
    }
  };

  loadA(0);
  for (int kc = 0; kc < NC; ++kc) {
    __syncthreads();
    writeA(kc);
    for (int idx = tid; idx < NR * 4; idx += 256) {
      int n = idx >> 2, p = idx & 3;
      *(f16x8*)(Bh + n * BKP + p * 8) =
          *(const f16x8*)(Wt + n * KPAD + kc * 32 + p * 8);
    }
    __syncthreads();
    if (kc + 1 < NC) loadA(kc + 1);
    f16x8 nf[MT];
#pragma unroll
    for (int mt = 0; mt < MT; ++mt) {
      int r = (wr * MT + mt) * 16 + ln;
      nf[mt] = *(const f16x8*)(Ah + r * BKP + quad * 8);
    }
#pragma unroll
    for (int j = 0; j < NT; ++j) {
      int n = (wc * NT + j) * 16 + ln;
      f16x8 wh = *(const f16x8*)(Bh + n * BKP + quad * 8);
#pragma unroll
      for (int mt = 0; mt < MT; ++mt)
        acc[mt][j] = __builtin_amdgcn_mfma_f32_16x16x32_f16(wh, nf[mt], acc[mt][j], 0, 0, 0);
    }
  }

  float* s_s = (float*)smem;
  float* s_q = s_s + NR;
  __syncthreads();
  if constexpr (STATS) {
    for (int c = tid; c < 2 * NR; c += 256) s_s[c] = 0.f;
    __syncthreads();
  }
  float rs[MT];
#pragma unroll
  for (int mt = 0; mt < MT; ++mt) {
    int nd = rowbase + (wr * MT + mt) * 16 + ln;
    rs[mt] = (rowscale != nullptr && nd < N_NODES) ? rowscale[nd] : 1.f;
  }
#pragma unroll
  for (int j = 0; j < NT; ++j) {
    int ch0 = (wc * NT + j) * 16 + quad * 4;
    bool cv = ch0 < NOUTr;
    float4 b4 = make_float4(0.f, 0.f, 0.f, 0.f);
    if (cv && bias != nullptr) b4 = *(const float4*)(bias + ch0);
    float sc[4] = {0.f, 0.f, 0.f, 0.f}, sq[4] = {0.f, 0.f, 0.f, 0.f};
#pragma unroll
    for (int mt = 0; mt < MT; ++mt) {
      int nd = rowbase + (wr * MT + mt) * 16 + ln;
      if (nd < N_NODES && cv) {
        float v0 = (acc[mt][j][0] + b4.x) * rs[mt];
        float v1 = (acc[mt][j][1] + b4.y) * rs[mt];
        float v2 = (acc[mt][j][2] + b4.z) * rs[mt];
        float v3 = (acc[mt][j][3] + b4.w) * rs[mt];
        if constexpr (F16OUT) {
          f16x4 o = {(_Float16)v0, (_Float16)v1, (_Float16)v2, (_Float16)v3};
          if constexpr (SPLIT) {
            _Float16* dp = (ch0 < 56)
                ? C16 + (size_t)nd * 64 + ch0
                : C16b + (size_t)nd * 64 + (ch0 - 56);
            *(f16x4*)dp = o;
          } else {
            *(f16x4*)(C16 + (size_t)nd * NOUTr + ch0) = o;
          }
        } else {
          float4 o = make_float4(v0, v1, v2, v3);
          *(float4*)(C + (size_t)nd * NOUTr + ch0) = o;
        }
        if constexpr (STATS) {
          sc[0] += v0; sq[0] = fmaf(v0, v0, sq[0]);
          sc[1] += v1; sq[1] = fmaf(v1, v1, sq[1]);
          sc[2] += v2; sq[2] = fmaf(v2, v2, sq[2]);
          sc[3] += v3; sq[3] = fmaf(v3, v3, sq[3]);
        }
      }
    }
    if constexpr (STATS) {
      if (cv) {
#pragma unroll
        for (int r = 0; r < 4; ++r) {
          float s = sc[r], q = sq[r];
          s += __shfl_xor(s, 1); q += __shfl_xor(q, 1);
          s += __shfl_xor(s, 2); q += __shfl_xor(q, 2);
          s += __shfl_xor(s, 4); q += __shfl_xor(q, 4);
          s += __shfl_xor(s, 8); q += __shfl_xor(q, 8);
          if (ln == 0) {
            atomicAdd(&s_s[ch0 + r], s);
            atomicAdd(&s_q[ch0 + r], q);
          }
        }
      }
    }
  }
  if constexpr (STATS) {
    __syncthreads();
    int rep = (blockIdx.x & (NREP - 1));
    for (int c = tid; c < NR; c += 256) {
      if (c < NOUTr) {
        atomicAdd(&sums[rep * NOUTr + c], s_s[c]);
        atomicAdd(&sqs[rep * NOUTr + c], s_q[c]);
      }
    }
  }
}

// ---------------- MFMA GEMM v2: B-resident LDS, barrier-free K-loop -------------
// (Measured best for K=112 h3 case: 34.8 KB LDS, y-tiled channels.)
template <int K, int KPAD, int NT, int MT, int MINW,
          bool BN, bool STATS, bool F16OUT>
__global__ __launch_bounds__(256, MINW) void k_mgemm2(
    const _Float16* __restrict__ A16, const _Float16* __restrict__ Wt,
    const float* __restrict__ bias, const float* __restrict__ bn_a,
    const float* __restrict__ bn_c, const float* __restrict__ rowscale,
    void* __restrict__ Cv, int NOUTr, float* __restrict__ sums,
    float* __restrict__ sqs) {
  constexpr int WR = 4;
  constexpr int BM = WR * MT * 16;
  constexpr int NR = NT * 16;
  constexpr int KPS = KPAD + 8;
  constexpr int NC = KPAD / 32;
  __shared__ __align__(16) _Float16 Bh[NR * KPS];

  const int tid = threadIdx.x;
  const int lane = tid & 63, wave = tid >> 6;
  const int quad = lane >> 4, ln = lane & 15;
  const int rowbase = blockIdx.x * BM;
  const int chbase = blockIdx.y * NR;

  for (int idx = tid; idx < NR * (KPAD / 8); idx += 256) {
    int n = idx / (KPAD / 8), p = idx % (KPAD / 8);
    *(f16x8*)(Bh + n * KPS + p * 8) =
        *(const f16x8*)(Wt + (size_t)(chbase + n) * KPAD + p * 8);
  }
  __syncthreads();

  fx4 acc[MT][NT];
#pragma unroll
  for (int mt = 0; mt < MT; ++mt)
#pragma unroll
    for (int j = 0; j < NT; ++j) acc[mt][j] = (fx4){0.f, 0.f, 0.f, 0.f};

  for (int kc = 0; kc < NC; ++kc) {
    const int k0 = kc * 32 + quad * 8;
    f16x8 af[MT];
#pragma unroll
    for (int mt = 0; mt < MT; ++mt) {
      int gi = rowbase + (wave * MT + mt) * 16 + ln;
      bool ok = (gi < N_NODES) && (k0 < K);
      f16x8 z;
#pragma unroll
      for (int t = 0; t < 8; ++t) z[t] = (_Float16)0;
      af[mt] = ok ? *(const f16x8*)(A16 + (size_t)gi * K + k0) : z;
    }
    if constexpr (BN) {
      if (k0 < K) {
        float4 ba0 = *(const float4*)(bn_a + k0);
        float4 ba1 = *(const float4*)(bn_a + k0 + 4);
        float4 bc0 = *(const float4*)(bn_c + k0);
        float4 bc1 = *(const float4*)(bn_c + k0 + 4);
        float av[8] = {ba0.x, ba0.y, ba0.z, ba0.w, ba1.x, ba1.y, ba1.z, ba1.w};
        float cv[8] = {bc0.x, bc0.y, bc0.z, bc0.w, bc1.x, bc1.y, bc1.z, bc1.w};
#pragma unroll
        for (int mt = 0; mt < MT; ++mt)
#pragma unroll
          for (int t = 0; t < 8; ++t)
            af[mt][t] = (_Float16)fmaxf(fmaf((float)af[mt][t], av[t], cv[t]), 0.f);
      }
    }
#pragma unroll
    for (int j = 0; j < NT; ++j) {
      f16x8 wh = *(const f16x8*)(Bh + (j * 16 + ln) * KPS + kc * 32 + quad * 8);
#pragma unroll
      for (int mt = 0; mt < MT; ++mt)
        acc[mt][j] = __builtin_amdgcn_mfma_f32_16x16x32_f16(wh, af[mt], acc[mt][j], 0, 0, 0);
    }
  }

  float* s_s = (float*)Bh;
  float* s_q = s_s + NR;
  __syncthreads();
  if constexpr (STATS) {
    for (int c = tid; c < 2 * NR; c += 256) s_s[c] = 0.f;
    __syncthreads();
  }
  float rs[MT];
#pragma unroll
  for (int mt = 0; mt < MT; ++mt) {
    int nd = rowbase + (wave * MT + mt) * 16 + ln;
    rs[mt] = (rowscale != nullptr && nd < N_NODES) ? rowscale[nd] : 1.f;
  }
  float* C = (float*)Cv;
  _Float16* C16 = (_Float16*)Cv;
#pragma unroll
  for (int j = 0; j < NT; ++j) {
    int lch = j * 16 + quad * 4;
    int ch0 = chbase + lch;
    bool cv = ch0 < NOUTr;
    float4 b4 = make_float4(0.f, 0.f, 0.f, 0.f);
    if (cv && bias != nullptr) b4 = *(const float4*)(bias + ch0);
    float sc[4] = {0.f, 0.f, 0.f, 0.f}, sq[4] = {0.f, 0.f, 0.f, 0.f};
#pragma unroll
    for (int mt = 0; mt < MT; ++mt) {
      int nd = rowbase + (wave * MT + mt) * 16 + ln;
      if (nd < N_NODES && cv) {
        float v0 = (acc[mt][j][0] + b4.x) * rs[mt];
        float v1 = (acc[mt][j][1] + b4.y) * rs[mt];
        float v2 = (acc[mt][j][2] + b4.z) * rs[mt];
        float v3 = (acc[mt][j][3] + b4.w) * rs[mt];
        if constexpr (F16OUT) {
          f16x4 o = {(_Float16)v0, (_Float16)v1, (_Float16)v2, (_Float16)v3};
          *(f16x4*)(C16 + (size_t)nd * NOUTr + ch0) = o;
        } else {
          float4 o = make_float4(v0, v1, v2, v3);
          *(float4*)(C + (size_t)nd * NOUTr + ch0) = o;
        }
        if constexpr (STATS) {
          sc[0] += v0; sq[0] = fmaf(v0, v0, sq[0]);
          sc[1] += v1; sq[1] = fmaf(v1, v1, sq[1]);
          sc[2] += v2; sq[2] = fmaf(v2, v2, sq[2]);
          sc[3] += v3; sq[3] = fmaf(v3, v3, sq[3]);
        }
      }
    }
    if constexpr (STATS) {
      if (cv) {
#pragma unroll
        for (int r = 0; r < 4; ++r) {
          float s = sc[r], q = sq[r];
          s += __shfl_xor(s, 1); q += __shfl_xor(q, 1);
          s += __shfl_xor(s, 2); q += __shfl_xor(q, 2);
          s += __shfl_xor(s, 4); q += __shfl_xor(q, 4);
          s += __shfl_xor(s, 8); q += __shfl_xor(q, 8);
          if (ln == 0) {
            atomicAdd(&s_s[lch + r], s);
            atomicAdd(&s_q[lch + r], q);
          }
        }
      }
    }
  }
  if constexpr (STATS) {
    __syncthreads();
    int rep = (blockIdx.x & (NREP - 1));
    for (int c = tid; c < NR; c += 256) {
      int gc = chbase + c;
      if (gc < NOUTr) {
        atomicAdd(&sums[rep * NOUTr + gc], s_s[c]);
        atomicAdd(&sqs[rep * NOUTr + gc], s_q[c]);
      }
    }
  }
}

// ---------------- conv2 aggregation, half-channel pass ----------------
__global__ __launch_bounds__(256) void k_agg2(
    const f16x8* __restrict__ t2x8, const float* __restrict__ dinv,
    const int* __restrict__ rowoff, const int* __restrict__ cnt,
    const int* __restrict__ csr, const float* __restrict__ b2,
    _Float16* __restrict__ g2, int off) {
  int lane = threadIdx.x & 63, wave = threadIdx.x >> 6;
  int j = lane >> 3, c = lane & 7;
  int i = blockIdx.x * 32 + wave * 8 + j;
  float di = dinv[i];
  int start = rowoff[i], len = cnt[i];
  f16x8 u = t2x8[i * 8 + c];
  float a0[8], a1[8], a2[8], a3[8];
#pragma unroll
  for (int t = 0; t < 8; ++t) { a0[t] = (float)u[t]; a1[t] = a2[t] = a3[t] = 0.f; }
  int e = 0;
  for (; e + 3 < len; e += 4) {
    int s0 = csr[start + e], s1 = csr[start + e + 1];
    int s2 = csr[start + e + 2], s3 = csr[start + e + 3];
    f16x8 u0 = t2x8[s0 * 8 + c];
    f16x8 u1 = t2x8[s1 * 8 + c];
    f16x8 u2 = t2x8[s2 * 8 + c];
    f16x8 u3 = t2x8[s3 * 8 + c];
#pragma unroll
    for (int t = 0; t < 8; ++t) {
      a0[t] += (float)u0[t]; a1[t] += (float)u1[t];
      a2[t] += (float)u2[t]; a3[t] += (float)u3[t];
    }
  }
  for (; e < len; ++e) {
    int s0 = csr[start + e];
    f16x8 u0 = t2x8[s0 * 8 + c];
#pragma unroll
    for (int t = 0; t < 8; ++t) a0[t] += (float)u0[t];
  }
  if (c < 7) {
    float4 blo = *(const float4*)(b2 + off + c * 8);
    float4 bhi = *(const float4*)(b2 + off + c * 8 + 4);
    float bb[8] = {blo.x, blo.y, blo.z, blo.w, bhi.x, bhi.y, bhi.z, bhi.w};
    f16x8 o;
#pragma unroll
    for (int t = 0; t < 8; ++t)
      o[t] = (_Float16)fmaf(di, a0[t] + a1[t] + a2[t] + a3[t], bb[t]);
    *(f16x8*)(g2 + (size_t)i * 112 + off + c * 8) = o;
  }
}

// ---------------- BN column stats (f16 input, for g2) ----------------
template <int C>
__global__ void k_colstats16(const _Float16* __restrict__ X, float* __restrict__ sums,
                             float* __restrict__ sqs) {
  int c = threadIdx.x;
  if (c >= C) return;
  int chunk = (N_NODES + gridDim.x - 1) / gridDim.x;
  int i0 = blockIdx.x * chunk;
  int i1 = min(N_NODES, i0 + chunk);
  float s = 0.f, q = 0.f;
  for (int i = i0; i < i1; ++i) {
    float v = (float)X[(size_t)i * C + c];
    s += v;
    q = fmaf(v, v, q);
  }
  int rep = (blockIdx.x & (NREP - 1));
  atomicAdd(&sums[rep * C + c], s);
  atomicAdd(&sqs[rep * C + c], q);
}

template <int C>
__global__ void k_bnfinal(const float* __restrict__ sums, const float* __restrict__ sqs,
                          const float* __restrict__ gamma, const float* __restrict__ beta,
                          float* __restrict__ bn_a, float* __restrict__ bn_c) {
  int c = threadIdx.x;
  if (c >= C) return;
  float s = 0.f, q = 0.f;
#pragma unroll
  for (int r = 0; r < NREP; ++r) {
    s += sums[r * C + c];
    q += sqs[r * C + c];
  }
  const float inv_n = 1.0f / (float)N_NODES;
  float mean = s * inv_n;
  float var = fmaxf(q * inv_n - mean * mean, 0.f);
  float rstd = 1.0f / sqrtf(var + 1e-5f);
  float a = gamma[c] * rstd;
  bn_a[c] = a;
  bn_c[c] = beta[c] - mean * a;
}

// ---------------- final (f16 h4) ----------------
__global__ void k_final(const _Float16* __restrict__ h4, const float* __restrict__ bn_a,
                        const float* __restrict__ bn_c, const float* __restrict__ w4,
                        const float* __restrict__ b4, float* __restrict__ out) {
  int lane = threadIdx.x & 63;
  int i = blockIdx.x * 4 + (threadIdx.x >> 6);
  float acc = fmaxf(fmaf((float)h4[(size_t)i * 100 + lane], bn_a[lane], bn_c[lane]), 0.f) * w4[lane];
  if (lane < 36) {
    int k = lane + 64;
    acc += fmaxf(fmaf((float)h4[(size_t)i * 100 + k], bn_a[k], bn_c[k]), 0.f) * w4[k];
  }
#pragma unroll
  for (int off = 32; off >= 1; off >>= 1) acc += __shfl_down(acc, off);
  if (lane == 0) out[i] = acc + b4[0];
}

extern "C" void kernel_launch(void* const* d_in, const int* in_sizes, int n_in,
                              void* d_out, int out_size, void* d_ws, size_t ws_size,
                              hipStream_t stream) {
  const float* x   = (const float*)d_in[0];
  const int*   ei  = (const int*)d_in[1];
  const float* W1  = (const float*)d_in[2];
  const float* b1  = (const float*)d_in[3];
  const float* W2  = (const float*)d_in[4];
  const float* b2  = (const float*)d_in[5];
  const float* l2w = (const float*)d_in[6];
  const float* l2b = (const float*)d_in[7];
  const float* l3w = (const float*)d_in[8];
  const float* l3b = (const float*)d_in[9];
  const float* l4w = (const float*)d_in[10];
  const float* l4b = (const float*)d_in[11];
  const float* g1  = (const float*)d_in[12];
  const float* be1 = (const float*)d_in[13];
  const float* g2w = (const float*)d_in[14];
  const float* be2 = (const float*)d_in[15];
  const float* g3  = (const float*)d_in[16];
  const float* be3 = (const float*)d_in[17];
  float* out = (float*)d_out;

  char* base = (char*)d_ws;
  size_t off = 0;
  auto alloc = [&](size_t bytes) -> char* {
    char* p = base + off;
    off = (off + bytes + 255) & ~(size_t)255;
    return p;
  };
  int*   cnt    = (int*)alloc((size_t)N_NODES * 4);
  int*   rowoff = (int*)alloc((size_t)N_NODES * 4);
  float* dinv   = (float*)alloc((size_t)N_NODES * 4);
  int*   csr    = (int*)alloc((size_t)N_EDGES * 4);
  unsigned* binned = (unsigned*)alloc((size_t)NBUCK * BCAP * 4);
  int*   gcount = (int*)alloc(NBUCK * 4);
  int*   gbase  = (int*)alloc(NBUCK * 4);
  float* stats  = (float*)alloc((size_t)NREP * 960 * 4);
  float* bnco   = (float*)alloc(960 * 4);
  _Float16* xs  = (_Float16*)alloc((size_t)N_NODES * 24 * 2);
  float* aggx   = (float*)alloc((size_t)N_NODES * 24 * 4);
  _Float16* h1  = (_Float16*)alloc((size_t)N_NODES * 256 * 2);  // f16; reused as h3
  _Float16* t2a = (_Float16*)alloc((size_t)N_NODES * 64 * 2);   // split ch 0-55 (+pad)
  _Float16* t2b = (_Float16*)alloc((size_t)N_NODES * 64 * 2);   // split ch 56-111 (+pad)
  _Float16* g2h = (_Float16*)alloc((size_t)N_NODES * 112 * 2);  // f16 conv2 output
  _Float16* h4  = (_Float16*)alloc((size_t)N_NODES * 112 * 2);  // f16 h4
  _Float16* wt2 = (_Float16*)alloc(112 * 256 * 2);
  _Float16* wt3 = (_Float16*)alloc(256 * 128 * 2);
  _Float16* wt4 = (_Float16*)alloc(112 * 256 * 2);

  float* sums1 = stats;
  float* sqs1  = sums1 + NREP * 112;
  float* sums2 = sqs1 + NREP * 112;
  float* sqs2  = sums2 + NREP * 256;
  float* sums3 = sqs2 + NREP * 256;
  float* sqs3  = sums3 + NREP * 112;
  float* bn_a1 = bnco + 0,   *bn_c1 = bnco + 112;
  float* bn_a2 = bnco + 224, *bn_c2 = bnco + 480;
  float* bn_a3 = bnco + 736, *bn_c3 = bnco + 848;

  hipMemsetAsync(gcount, 0, NBUCK * 4, stream);
  hipMemsetAsync(stats, 0, (size_t)NREP * 960 * 4, stream);

  k_bin<<<NBUCK, 256, 0, stream>>>(ei, binned, gcount);
  k_bscan<<<1, 256, 0, stream>>>(gcount, gbase);
  k_csr<<<NBUCK, 256, 0, stream>>>(binned, gcount, gbase, rowoff, cnt, dinv, csr);

  k_wcvt<256, 256, 112, 112><<<112, 256, 0, stream>>>(W2, wt2);
  k_wcvt<112, 128, 256, 256><<<128, 256, 0, stream>>>(l2w, wt3);
  k_wcvt<256, 256, 100, 112><<<112, 256, 0, stream>>>(l3w, wt4);

  k_xpad<<<(N_NODES * 24 + 255) / 256, 256, 0, stream>>>(x, dinv, xs);
  k_aggx<<<(N_NODES + 83) / 84, 256, 0, stream>>>((const f16x8*)xs, dinv, rowoff,
                                                  cnt, csr, aggx);
  k_gemm1<<<3125, 256, 0, stream>>>((const float4*)aggx, W1, b1, h1);

  // t2 = dinv*(h1@W2) f16 split: v1 pipelined, 25.6 KB LDS (measured best)
  k_mgemm<256, 256, 7, 2, 4, 1, 4, false, false, true, true>
      <<<782, 256, 0, stream>>>(h1, wt2, nullptr, nullptr, nullptr, dinv,
                                t2a, t2b, 112, nullptr, nullptr);
  k_agg2<<<3125, 256, 0, stream>>>((const f16x8*)t2a, dinv, rowoff, cnt, csr, b2,
                                   g2h, 0);
  k_agg2<<<3125, 256, 0, stream>>>((const f16x8*)t2b, dinv, rowoff, cnt, csr, b2,
                                   g2h, 56);

  k_colstats16<112><<<1600, 128, 0, stream>>>(g2h, sums1, sqs1);
  k_bnfinal<112><<<1, 128, 0, stream>>>(sums1, sqs1, g1, be1, bn_a1, bn_c1);

  // h3 = relu(bn1(g2))@lin2_w + b: v2 barrier-free, 2 y-tiles (measured best)
  k_mgemm2<112, 128, 8, 2, 3, true, true, true>
      <<<dim3(782, 2), 256, 0, stream>>>(g2h, wt3, l2b, bn_a1, bn_c1, nullptr,
                                         h1, 256, sums2, sqs2);
  k_bnfinal<256><<<1, 256, 0, stream>>>(sums2, sqs2, g2w, be2, bn_a2, bn_c2);

  // h4 = relu(bn2(h3))@lin3_w + b: v1 pipelined, f16-out
  k_mgemm<256, 256, 7, 2, 4, 1, 4, true, true, true, false>
      <<<782, 256, 0, stream>>>(h1, wt4, l3b, bn_a2, bn_c2, nullptr,
                                h4, nullptr, 100, sums3, sqs3);
  k_bnfinal<100><<<1, 128, 0, stream>>>(sums3, sqs3, g3, be3, bn_a3, bn_c3);

  k_final<<<25000, 256, 0, stream>>>(h4, bn_a3, bn_c3, l4w, l4b, out);
}